// Round 3
// baseline (448.914 us; speedup 1.0000x reference)
//
#include <hip/hip_runtime.h>
#include <hip/hip_bf16.h>

// ---------- helpers ----------

__device__ __forceinline__ unsigned short f2bf(float f) {
    unsigned u = __float_as_uint(f);
    unsigned r = u + 0x7fffu + ((u >> 16) & 1u);
    return (unsigned short)(r >> 16);
}

typedef __bf16 bf16_t;
typedef bf16_t bf16x8 __attribute__((ext_vector_type(8)));
typedef float f32x16 __attribute__((ext_vector_type(16)));

typedef const __attribute__((address_space(1))) unsigned int* gptr_t;
typedef __attribute__((address_space(3))) unsigned int* lptr_t;

__device__ __forceinline__ void gload_lds16(const void* g, void* l) {
    __builtin_amdgcn_global_load_lds((gptr_t)g, (lptr_t)l, 16, 0, 0);
}

// ---------- kernel 1: column-wise max of |x| ----------
__global__ void colmax_kernel(const float* __restrict__ src, int rows, int cols,
                              unsigned int* __restrict__ dst, int rows_per_block) {
    int c = (blockIdx.x * blockDim.x + threadIdx.x) * 4;
    if (c >= cols) return;
    int r0 = blockIdx.y * rows_per_block;
    int r1 = min(r0 + rows_per_block, rows);
    float m0 = 0.f, m1 = 0.f, m2 = 0.f, m3 = 0.f;
    const float* p = src + (size_t)r0 * cols + c;
    for (int r = r0; r < r1; ++r, p += cols) {
        float4 v = *(const float4*)p;
        m0 = fmaxf(m0, fabsf(v.x));
        m1 = fmaxf(m1, fabsf(v.y));
        m2 = fmaxf(m2, fabsf(v.z));
        m3 = fmaxf(m3, fabsf(v.w));
    }
    atomicMax(dst + c + 0, __float_as_uint(m0));
    atomicMax(dst + c + 1, __float_as_uint(m1));
    atomicMax(dst + c + 2, __float_as_uint(m2));
    atomicMax(dst + c + 3, __float_as_uint(m3));
}

// ---------- kernel 1b: fused column-max of |W| + W -> bf16 ----------
__global__ void wmaxconv_kernel(const float* __restrict__ W, unsigned int* __restrict__ mw,
                                unsigned short* __restrict__ Wb, int rows, int cols,
                                int rows_per_block) {
    int c = (blockIdx.x * blockDim.x + threadIdx.x) * 4;
    if (c >= cols) return;
    int r0 = blockIdx.y * rows_per_block;
    int r1 = min(r0 + rows_per_block, rows);
    float m0 = 0.f, m1 = 0.f, m2 = 0.f, m3 = 0.f;
    const float* p = W + (size_t)r0 * cols + c;
    unsigned short* q = Wb + (size_t)r0 * cols + c;
    for (int r = r0; r < r1; ++r, p += cols, q += cols) {
        float4 v = *(const float4*)p;
        ushort4 o;
        o.x = f2bf(v.x); o.y = f2bf(v.y); o.z = f2bf(v.z); o.w = f2bf(v.w);
        *(ushort4*)q = o;
        m0 = fmaxf(m0, fabsf(v.x));
        m1 = fmaxf(m1, fabsf(v.y));
        m2 = fmaxf(m2, fabsf(v.z));
        m3 = fmaxf(m3, fabsf(v.w));
    }
    atomicMax(mw + c + 0, __float_as_uint(m0));
    atomicMax(mw + c + 1, __float_as_uint(m1));
    atomicMax(mw + c + 2, __float_as_uint(m2));
    atomicMax(mw + c + 3, __float_as_uint(m3));
}

// ---------- kernel 2: s = sqrt(max_act / clip(max_w, EPS)) ----------
__global__ void s_kernel(const unsigned int* __restrict__ ma,
                         const unsigned int* __restrict__ mw,
                         float* __restrict__ s, int n) {
    int i = blockIdx.x * blockDim.x + threadIdx.x;
    if (i < n) {
        float a = __uint_as_float(ma[i]);
        float w = fmaxf(__uint_as_float(mw[i]), 1e-8f);
        s[i] = sqrtf(a / w);
    }
}

// ---------- kernel 3: 2:4 prune of (x/s), emit bf16(x)*mask ----------
__global__ void prune_kernel(const float* __restrict__ x, const float* __restrict__ s,
                             unsigned short* __restrict__ xsp, size_t ngroups, int cols) {
    size_t g = (size_t)blockIdx.x * blockDim.x + threadIdx.x;
    size_t stride = (size_t)gridDim.x * blockDim.x;
    for (; g < ngroups; g += stride) {
        size_t e = g * 4;
        int cb = (int)(e & (size_t)(cols - 1));
        float4 v = *(const float4*)(x + e);
        float4 sv = *(const float4*)(s + cb);
        float a0 = fabsf(v.x / sv.x);
        float a1 = fabsf(v.y / sv.y);
        float a2 = fabsf(v.z / sv.z);
        float a3 = fabsf(v.w / sv.w);
        int r0 = 0, r1 = 0, r2 = 0, r3 = 0;
        if (a1 > a0) r0++; else r1++;
        if (a2 > a0) r0++; else r2++;
        if (a3 > a0) r0++; else r3++;
        if (a2 > a1) r1++; else r2++;
        if (a3 > a1) r1++; else r3++;
        if (a3 > a2) r2++; else r3++;
        ushort4 o;
        o.x = (r0 < 2) ? f2bf(v.x) : (unsigned short)0;
        o.y = (r1 < 2) ? f2bf(v.y) : (unsigned short)0;
        o.z = (r2 < 2) ? f2bf(v.z) : (unsigned short)0;
        o.w = (r3 < 2) ? f2bf(v.w) : (unsigned short)0;
        *(ushort4*)(xsp + e) = o;
    }
}

// ---------- kernel 5: 256x256 bf16 B^T GEMM, 32x32x16 MFMA, frag-major LDS ----------
// C[m,n] = sum_k A[m,k]*B[n,k]. 8 waves (2Mx4N), BK=64, 2 phases/K-tile.
// LDS layout: fragment-major — frag (rowblk g, kk) of a tile occupies bytes
// [(g*4+kk)*1024, ...+1024), lane l's 16B at +l*16 holding row g*32+(l&31),
// K = kk*16 + 8*(l>>5) .. +7 (the exact 32x32x16 MFMA operand layout).
// Staged via global_load_lds with per-lane (row-strided) global addresses.

// stage region r0 = {kk r0, r0+1} of the tile at k-elem-offset kt into (bufA,bufB).
#define STAGE(bufA, bufB, kt, r0)                                                  \
    do {                                                                           \
        gload_lds16(gA + (kt) + (r0) * 16,      (char*)&(bufA)[(wid * 4 + (r0)) * 512]);     \
        gload_lds16(gA + (kt) + (r0) * 16 + 16, (char*)&(bufA)[(wid * 4 + (r0) + 1) * 512]); \
        gload_lds16(gB + (kt) + (r0) * 16,      (char*)&(bufB)[(wid * 4 + (r0)) * 512]);     \
        gload_lds16(gB + (kt) + (r0) * 16 + 16, (char*)&(bufB)[(wid * 4 + (r0) + 1) * 512]); \
    } while (0)

#define PHASE(rdA, rdB, r0, STAGE_STMT)                                            \
    do {                                                                           \
        bf16x8 af[4][2], bv[2][2];                                                 \
        _Pragma("unroll") for (int mm = 0; mm < 4; ++mm)                           \
            _Pragma("unroll") for (int q = 0; q < 2; ++q)                          \
                af[mm][q] = *(const bf16x8*)&(rdA)[((wr * 4 + mm) * 4 + (r0) + q) * 512 + l * 8]; \
        _Pragma("unroll") for (int nn = 0; nn < 2; ++nn)                           \
            _Pragma("unroll") for (int q = 0; q < 2; ++q)                          \
                bv[nn][q] = *(const bf16x8*)&(rdB)[((wc * 2 + nn) * 4 + (r0) + q) * 512 + l * 8]; \
        STAGE_STMT;                                                                \
        asm volatile("s_waitcnt vmcnt(8)" ::: "memory");                           \
        __builtin_amdgcn_s_barrier();                                              \
        asm volatile("s_waitcnt lgkmcnt(0)" ::: "memory");                         \
        __builtin_amdgcn_sched_barrier(0);                                         \
        __builtin_amdgcn_s_setprio(1);                                             \
        _Pragma("unroll") for (int mm = 0; mm < 4; ++mm)                           \
            _Pragma("unroll") for (int nn = 0; nn < 2; ++nn)                       \
                _Pragma("unroll") for (int q = 0; q < 2; ++q)                      \
                    acc[mm][nn] = __builtin_amdgcn_mfma_f32_32x32x16_bf16(         \
                        af[mm][q], bv[nn][q], acc[mm][nn], 0, 0, 0);               \
        __builtin_amdgcn_s_setprio(0);                                             \
        __builtin_amdgcn_s_barrier();                                              \
        asm volatile("" ::: "memory");                                             \
        __builtin_amdgcn_sched_barrier(0);                                         \
    } while (0)

__global__ __launch_bounds__(512, 2) void gemm_bt256(
        const unsigned short* __restrict__ A,
        const unsigned short* __restrict__ B,
        float* __restrict__ C, int M, int N, int K) {
    __shared__ unsigned short sA[2][16384];
    __shared__ unsigned short sB[2][16384];
    const int tid = threadIdx.x;
    const int l = tid & 63;
    const int wid = tid >> 6;
    const int wr = wid >> 2;
    const int wc = wid & 3;

    // bijective XCD swizzle (nwg % 8 == 0)
    const int nbx = N >> 8, nby = M >> 8;
    const int cpx = (nbx * nby) >> 3;
    const int swz = ((int)blockIdx.x & 7) * cpx + ((int)blockIdx.x >> 3);
    const int by = swz % nby;
    const int bx = swz / nby;
    const long browBase = (long)by << 8;
    const long bcolBase = (long)bx << 8;

    const int NT = K >> 6;

    // per-lane staging source base: wave `wid` stages A/B rows [wid*32, wid*32+32)
    const unsigned short* gA = A + (size_t)(browBase + wid * 32 + (l & 31)) * K + ((l >> 5) * 8);
    const unsigned short* gB = B + (size_t)(bcolBase + wid * 32 + (l & 31)) * K + ((l >> 5) * 8);

    f32x16 acc[4][2] = {};

    // prologue: R1(0), R2(0) -> buf0; R1(1) -> buf1; drain R1(0)
    STAGE(sA[0], sB[0], 0, 0);
    STAGE(sA[0], sB[0], 0, 2);
    STAGE(sA[1], sB[1], 64, 0);
    asm volatile("s_waitcnt vmcnt(8)" ::: "memory");
    __builtin_amdgcn_s_barrier();
    asm volatile("" ::: "memory");
    __builtin_amdgcn_sched_barrier(0);

    for (int t = 0; t < NT; ++t) {
        const int cur = t & 1;
        const unsigned short* rA = sA[cur];
        const unsigned short* rB = sB[cur];
        unsigned short* nA = (unsigned short*)sA[cur ^ 1];
        unsigned short* nB = (unsigned short*)sB[cur ^ 1];
        unsigned short* cA = (unsigned short*)sA[cur];
        unsigned short* cB = (unsigned short*)sB[cur];
        // clamped stage offsets keep the vmcnt ledger uniform at the tail
        const int k1 = (t + 1 < NT ? t + 1 : NT - 1) << 6;
        const int k2 = (t + 2 < NT ? t + 2 : NT - 1) << 6;

        // p1: read kk{0,1} of cur; stage R2(t+1) into next buffer
        PHASE(rA, rB, 0, STAGE(nA, nB, k1, 2));
        // p2: read kk{2,3} of cur; stage R1(t+2) into cur buffer (region consumed at p1)
        PHASE(rA, rB, 2, STAGE(cA, cB, k2, 0));
    }

    // epilogue: 32x32 C/D layout: col = lane&31, row = (reg&3) + 8*(reg>>2) + 4*(lane>>5)
    const int ec = l & 31;
    const int erh = (l >> 5) * 4;
#pragma unroll
    for (int mm = 0; mm < 4; ++mm) {
#pragma unroll
        for (int nn = 0; nn < 2; ++nn) {
            long row0 = browBase + wr * 128 + mm * 32;
            long col = bcolBase + wc * 64 + nn * 32 + ec;
#pragma unroll
            for (int r = 0; r < 16; ++r) {
                long row = row0 + (r & 3) + 8 * (r >> 2) + erh;
                C[row * N + col] = acc[mm][nn][r];
            }
        }
    }
}

// ---------- launch ----------
extern "C" void kernel_launch(void* const* d_in, const int* in_sizes, int n_in,
                              void* d_out, int out_size, void* d_ws, size_t ws_size,
                              hipStream_t stream) {
    const float* x = (const float*)d_in[0];
    const float* W = (const float*)d_in[1];
    float* out = (float*)d_out;

    const int K = 4096;
    const int Nout = in_sizes[1] / K;             // 4096
    const size_t Mrows = (size_t)in_sizes[0] / K; // 8192

    char* ws = (char*)d_ws;
    unsigned short* Xsp = (unsigned short*)ws;
    unsigned short* Wb = (unsigned short*)(ws + Mrows * K * 2);
    unsigned int* ma = (unsigned int*)(ws + Mrows * K * 2 + (size_t)Nout * K * 2);
    unsigned int* mw = ma + K;
    float* s = (float*)(mw + K);

    hipMemsetAsync(ma, 0, 2 * K * sizeof(unsigned int), stream);

    dim3 blk(256);
    {
        dim3 gx(K / 1024, (unsigned)(Mrows / 64));
        colmax_kernel<<<gx, blk, 0, stream>>>(x, (int)Mrows, K, ma, 64);
        dim3 gw(K / 1024, Nout / 64);
        wmaxconv_kernel<<<gw, blk, 0, stream>>>(W, mw, Wb, Nout, K, 64);
    }
    s_kernel<<<dim3((K + 255) / 256), blk, 0, stream>>>(ma, mw, s, K);
    {
        size_t ngroups = Mrows * K / 4;
        prune_kernel<<<dim3(2048), blk, 0, stream>>>(x, s, Xsp, ngroups, K);
    }
    {
        dim3 g((unsigned)((Mrows / 256) * (Nout / 256)));
        gemm_bt256<<<g, dim3(512), 0, stream>>>(Xsp, Wb, out, (int)Mrows, Nout, K);
    }
}